// Round 1
// 1964.382 us; speedup vs baseline: 2.0000x; 2.0000x over previous
//
#include <hip/hip_runtime.h>
#include <stdint.h>

#define H      160
#define G3     480
#define NCH    10
#define TCH    20
#define CC     200
#define NCLS   16
#define NLAYERS 160
#define NLEVELS 161
#define NFLAGS (NLEVELS * NCH + 1)   // level-t flags + xl flag

typedef unsigned int u32;

// static device scratch — flags re-zeroed by zero_flags each call.
// All cross-block traffic goes through agent-scope relaxed atomics (sc0/sc1
// path -> coherence point); ordering is provided by __syncthreads()'s
// vmcnt(0) drain on the producer and the post-poll barrier on the consumer.
__device__ float g_seq[NLEVELS * NCH * H];   // [161][10][160]
__device__ float g_xlb[H];
__device__ int   g_flg[NFLAGS];

__device__ __forceinline__ float sigm(float x){ return 1.0f / (1.0f + expf(-x)); }

__device__ __forceinline__ void stf(float* p, float v){
  __hip_atomic_store(p, v, __ATOMIC_RELAXED, __HIP_MEMORY_SCOPE_AGENT);
}
__device__ __forceinline__ float ldf(float* p){
  return __hip_atomic_load(p, __ATOMIC_RELAXED, __HIP_MEMORY_SCOPE_AGENT);
}
__device__ __forceinline__ void st_flag(int* p, int v){
  // release ordering achieved by the __syncthreads() (vmcnt(0) drain of the
  // sc1 write-through value stores) that precedes every call site — no wbl2.
  __hip_atomic_store(p, v, __ATOMIC_RELAXED, __HIP_MEMORY_SCOPE_AGENT);
}
// Relaxed spin: no buffer_inv per poll (the acquire-per-poll invalidation
// storm from ~150 concurrent spinners is the theorized 23us/step cost).
// A periodic ACQUIRE every 512 polls guarantees forward progress even if
// relaxed agent loads were ever served from a stale local cache; at ~0.3us
// per relaxed poll it fires every ~150us per spinning block — negligible
// background traffic and statistically never in the final handoff window.
__device__ __forceinline__ void wait_flag(int* p){
  int it = 0;
  while (__hip_atomic_load(p, __ATOMIC_RELAXED, __HIP_MEMORY_SCOPE_AGENT) == 0){
    if (++it == 512){
      it = 0;
      (void)__hip_atomic_load(p, __ATOMIC_ACQUIRE, __HIP_MEMORY_SCOPE_AGENT);
    }
  }
}

__device__ __forceinline__ float dot160(const float4* __restrict__ w, const float* v){
  float a0 = 0.f, a1 = 0.f;
#pragma unroll
  for (int q = 0; q < 40; q += 2){
    float4 wa = w[q], wb = w[q+1];
    float4 va = *(const float4*)(v + 4*q);
    float4 vb = *(const float4*)(v + 4*q + 4);
    a0 = fmaf(wa.x, va.x, a0); a0 = fmaf(wa.y, va.y, a0);
    a0 = fmaf(wa.z, va.z, a0); a0 = fmaf(wa.w, va.w, a0);
    a1 = fmaf(wb.x, vb.x, a1); a1 = fmaf(wb.y, vb.y, a1);
    a1 = fmaf(wb.z, vb.z, a1); a1 = fmaf(wb.w, vb.w, a1);
  }
  return a0 + a1;
}

extern "C" __global__ void zero_flags_kernel(){
  int i = threadIdx.x + blockIdx.x * blockDim.x;
  if (i < NFLAGS) g_flg[i] = 0;
}

// launch_bounds(512,1): 1 block/CU -> 2 waves/SIMD -> 256-VGPR budget, so
// float4 whhr[40] (160 VGPRs) is genuinely register-resident (at the old
// (512,2) cap of 128 VGPRs it spilled to scratch and was re-read every step).
// 171 blocks on 256 CUs: every block still gets its own CU.
extern "C" __global__ __launch_bounds__(512, 1)
void spectral_wave(
  const float* __restrict__ x,
  const float* __restrict__ b_wih, const float* __restrict__ b_whh,
  const float* __restrict__ b_bih, const float* __restrict__ b_bhh,
  const float* __restrict__ g_wih, const float* __restrict__ g_whh,
  const float* __restrict__ g_bih, const float* __restrict__ g_bhh,
  const float* __restrict__ g3_wih, const float* __restrict__ g3_whh,
  const float* __restrict__ g3_bih, const float* __restrict__ g3_bhh,
  const float* __restrict__ bn_gamma, const float* __restrict__ bn_beta,
  const float* __restrict__ bn_mean,  const float* __restrict__ bn_var,
  const float* __restrict__ fc_w, const float* __restrict__ fc_b,
  const float* __restrict__ reg_w, const float* __restrict__ reg_b,
  float* __restrict__ out)
{
  const int tid = threadIdx.x;
  const int bid = blockIdx.x;
  int* flg = g_flg;

  __shared__ __align__(16) float sx[H];
  __shared__ __align__(16) float sh[H];
  __shared__ float spre[2*H];
  __shared__ float sxn[H];
  __shared__ float shn[H];
  __shared__ float sxc[H];

  if (bid < NLAYERS) {
    // ---------------- g3 layer block: layer l ----------------
    const int l = bid;
    const float4* wih_row = (const float4*)(g3_wih + ((size_t)l*G3 + tid)*H);
    const float4* whh_row = (const float4*)(g3_whh + ((size_t)l*G3 + tid)*H);
    float4 whhr[40];
    float bihj = 0.f, bhhj = 0.f;
    if (tid < G3){
#pragma unroll
      for (int q = 0; q < 40; q++) whhr[q] = whh_row[q];
      bihj = g3_bih[l*G3 + tid];
      bhhj = g3_bhh[l*G3 + tid];
    }
    if (tid < H) sh[tid] = 0.f;

    // prefetch W_ih into L1/L2 ahead of the wavefront (first-touch HBM off the critical path)
    float pf = 0.f;
    if (tid < G3){
#pragma unroll
      for (int q = 0; q < 40; q++) pf += wih_row[q].x;
    }
    if (pf == 1.0e30f) sxc[0] = pf;   // never true; defeats DCE
    __syncthreads();

    float hsum = 0.f;
    float* seq_in  = g_seq + (size_t)l * NCH * H;
    float* seq_out = g_seq + (size_t)(l+1) * NCH * H;
    int* f_in  = flg + l * NCH;
    int* f_out = flg + (l+1) * NCH;

    for (int t = 0; t < NCH; t++){
      // recurrent dot precomputed (register-resident whh) while waiting for input
      float ahv = 0.f;
      if (tid < G3) ahv = bhhj + dot160(whhr, sh);
      if (tid == 0) wait_flag(&f_in[t]);
      __syncthreads();
      if (tid < H) sx[tid] = ldf(&seq_in[t*H + tid]);
      __syncthreads();
      if (tid < G3){
        float ax = bihj + dot160(wih_row, sx);
        if (tid < 2*H) spre[tid] = ax + ahv;
        else { sxn[tid - 2*H] = ax; shn[tid - 2*H] = ahv; }
      }
      __syncthreads();
      if (tid < H){
        float r = sigm(spre[tid]);
        float z = sigm(spre[H + tid]);
        float n = tanhf(sxn[tid] + r * shn[tid]);
        float h = (1.f - z) * n + z * sh[tid];
        sh[tid] = h;
        hsum += h;
        stf(&seq_out[t*H + tid], h);
      }
      __syncthreads();                   // vmcnt(0) drain: values at LLC before flag
      if (tid == 0) st_flag(&f_out[t], 1);
    }

    if (l == NLAYERS - 1){
      // epilogue: x_cat_l, wait x_l, BN+ReLU, heads
      if (tid < H) sxc[tid] = fmaxf(hsum * (1.0f / NCH), 0.f);
      if (tid == 0) wait_flag(&flg[NLEVELS*NCH]);
      __syncthreads();
      if (tid < H){
        float xl   = ldf(&g_xlb[tid]);
        float xnew = xl * sxc[tid];
        float xbn  = (xnew - bn_mean[tid]) * rsqrtf(bn_var[tid] + 1e-5f)
                     * bn_gamma[tid] + bn_beta[tid];
        sx[tid] = fmaxf(xbn, 0.f);       // xr
      }
      __syncthreads();
      if (tid < NCLS + CC){
        const float* wrow; float acc;
        if (tid < NCLS){ wrow = fc_w + (size_t)tid * H; acc = fc_b[tid]; }
        else           { wrow = reg_w + (size_t)(tid - NCLS) * H; acc = reg_b[tid - NCLS]; }
#pragma unroll
        for (int q = 0; q < 40; q++){
          float4 wv = *(const float4*)(wrow + 4*q);
          float4 xv = *(const float4*)(sx + 4*q);
          acc = fmaf(wv.x, xv.x, acc);
          acc = fmaf(wv.y, xv.y, acc);
          acc = fmaf(wv.z, xv.z, acc);
          acc = fmaf(wv.w, xv.w, acc);
        }
        out[tid] = acc;                  // f32 output
      }
    }
  } else if (bid < NLAYERS + NCH) {
    // ---------------- branch GRU block b ----------------
    const int b = bid - NLAYERS;
    const float4* whh_row = (const float4*)(b_whh + ((size_t)b*G3 + tid)*H);
    float4 whhr[40];
    float wij = 0.f, bihj = 0.f, bhhj = 0.f;
    if (tid < G3){
#pragma unroll
      for (int q = 0; q < 40; q++) whhr[q] = whh_row[q];
      wij  = b_wih[b*G3 + tid];
      bihj = b_bih[b*G3 + tid];
      bhhj = b_bhh[b*G3 + tid];
    }
    if (tid < H) sh[tid] = 0.f;
    __syncthreads();
    for (int t = 0; t < TCH; t++){
      float xv = x[b*TCH + t];
      if (tid < G3){
        float ax = fmaf(xv, wij, bihj);
        float ah = bhhj + dot160(whhr, sh);
        if (tid < 2*H) spre[tid] = ax + ah;
        else { sxn[tid - 2*H] = ax; shn[tid - 2*H] = ah; }
      }
      __syncthreads();
      if (tid < H){
        float r = sigm(spre[tid]);
        float z = sigm(spre[H + tid]);
        float n = tanhf(sxn[tid] + r * shn[tid]);
        float h = (1.f - z) * n + z * sh[tid];
        sh[tid] = h;
        if (t == TCH - 1) stf(&g_seq[(size_t)b*H + tid], h);   // level 0, chunk b
      }
      __syncthreads();                   // drains the level-0 stores before flag
    }
    if (tid == 0) st_flag(&flg[b], 1);
  } else {
    // ---------------- full-x GRU (200 steps) ----------------
    const float4* whh_row = (const float4*)(g_whh + (size_t)tid * H);
    float4 whhr[40];
    float wij = 0.f, bihj = 0.f, bhhj = 0.f;
    if (tid < G3){
#pragma unroll
      for (int q = 0; q < 40; q++) whhr[q] = whh_row[q];
      wij  = g_wih[tid];
      bihj = g_bih[tid];
      bhhj = g_bhh[tid];
    }
    if (tid < H) sh[tid] = 0.f;
    __syncthreads();
    float hsum = 0.f;
    for (int t = 0; t < CC; t++){
      float xv = x[t];
      if (tid < G3){
        float ax = fmaf(xv, wij, bihj);
        float ah = bhhj + dot160(whhr, sh);
        if (tid < 2*H) spre[tid] = ax + ah;
        else { sxn[tid - 2*H] = ax; shn[tid - 2*H] = ah; }
      }
      __syncthreads();
      if (tid < H){
        float r = sigm(spre[tid]);
        float z = sigm(spre[H + tid]);
        float n = tanhf(sxn[tid] + r * shn[tid]);
        float h = (1.f - z) * n + z * sh[tid];
        sh[tid] = h;
        hsum += h;
      }
      __syncthreads();
    }
    if (tid < H) stf(&g_xlb[tid], hsum * (1.0f / CC));
    __syncthreads();                     // drain x_l stores before flag
    if (tid == 0) st_flag(&flg[NLEVELS*NCH], 1);
  }
}

extern "C" void kernel_launch(void* const* d_in, const int* in_sizes, int n_in,
                              void* d_out, int out_size, void* d_ws, size_t ws_size,
                              hipStream_t stream) {
  (void)in_sizes; (void)n_in; (void)out_size; (void)d_ws; (void)ws_size;

  hipLaunchKernelGGL(zero_flags_kernel, dim3((NFLAGS + 255)/256), dim3(256), 0, stream);

  dim3 grid(NLAYERS + NCH + 1);
  dim3 block(512);
  hipLaunchKernelGGL(spectral_wave, grid, block, 0, stream,
    (const float*)d_in[0],
    (const float*)d_in[1],  (const float*)d_in[2],
    (const float*)d_in[3],  (const float*)d_in[4],
    (const float*)d_in[5],  (const float*)d_in[6],
    (const float*)d_in[7],  (const float*)d_in[8],
    (const float*)d_in[9],  (const float*)d_in[10],
    (const float*)d_in[11], (const float*)d_in[12],
    (const float*)d_in[13], (const float*)d_in[14],
    (const float*)d_in[15], (const float*)d_in[16],
    (const float*)d_in[17], (const float*)d_in[18],
    (const float*)d_in[19], (const float*)d_in[20],
    (float*)d_out);
}

// Round 2
// 1910.759 us; speedup vs baseline: 2.0562x; 1.0281x over previous
//
#include <hip/hip_runtime.h>
#include <stdint.h>

#define H      160
#define G3     480
#define NCH    10
#define TCH    20
#define CC     200
#define NCLS   16
#define NLAYERS 160
#define NLEVELS 161
#define NSEQ   (NLEVELS * NCH * H)

// Canary: a quiet-NaN bit pattern. GRU hidden states are NEVER NaN
// (sigmoid/tanh of finite inputs, finite weights), so any legit value
// differs. Compare on the BIT PATTERN (NaN float-compare is always false).
#define CANARY 0x7fbadbadu

// static device scratch — re-poisoned by poison_kernel each call (stream-ordered).
// Handoff protocol: producers store h-values with relaxed agent-scope atomics
// (write-through to the coherence point); consumers per-lane spin on their OWN
// word until it is != canary. The polled value IS the data: one one-way LLC
// propagation per handoff, zero fences, zero flags, no producer drain-before-
// flag, no separate data reload. Per-location coherence is sufficient.
__device__ float g_seq[NSEQ];   // [161][10][160]
__device__ float g_xlb[H];

__device__ __forceinline__ float sigm(float x){ return 1.0f / (1.0f + expf(-x)); }

__device__ __forceinline__ void stf(float* p, float v){
  __hip_atomic_store(p, v, __ATOMIC_RELAXED, __HIP_MEMORY_SCOPE_AGENT);
}
__device__ __forceinline__ float ldf(float* p){
  return __hip_atomic_load(p, __ATOMIC_RELAXED, __HIP_MEMORY_SCOPE_AGENT);
}
// spin until *p != canary; returns the value. Atomic load keeps the compiler
// from hoisting it out of the loop.
__device__ __forceinline__ float poll_val(float* p){
  float v;
  do { v = ldf(p); } while (__float_as_uint(v) == CANARY);
  return v;
}

__device__ __forceinline__ float dot160(const float4* __restrict__ w, const float* v){
  float a0 = 0.f, a1 = 0.f;
#pragma unroll
  for (int q = 0; q < 40; q += 2){
    float4 wa = w[q], wb = w[q+1];
    float4 va = *(const float4*)(v + 4*q);
    float4 vb = *(const float4*)(v + 4*q + 4);
    a0 = fmaf(wa.x, va.x, a0); a0 = fmaf(wa.y, va.y, a0);
    a0 = fmaf(wa.z, va.z, a0); a0 = fmaf(wa.w, va.w, a0);
    a1 = fmaf(wb.x, vb.x, a1); a1 = fmaf(wb.y, vb.y, a1);
    a1 = fmaf(wb.z, vb.z, a1); a1 = fmaf(wb.w, vb.w, a1);
  }
  return a0 + a1;
}

extern "C" __global__ void poison_kernel(){
  int i = threadIdx.x + blockIdx.x * blockDim.x;
  float c = __uint_as_float(CANARY);
  if (i < NSEQ) stf(&g_seq[i], c);
  if (i < H)    stf(&g_xlb[i], c);
}

// (512,1): 1 block/CU, 2 waves/SIMD -> up to 256-VGPR budget for whhr.
// 171 blocks on 256 CUs: every block gets its own CU.
extern "C" __global__ __launch_bounds__(512, 1)
void spectral_wave(
  const float* __restrict__ x,
  const float* __restrict__ b_wih, const float* __restrict__ b_whh,
  const float* __restrict__ b_bih, const float* __restrict__ b_bhh,
  const float* __restrict__ g_wih, const float* __restrict__ g_whh,
  const float* __restrict__ g_bih, const float* __restrict__ g_bhh,
  const float* __restrict__ g3_wih, const float* __restrict__ g3_whh,
  const float* __restrict__ g3_bih, const float* __restrict__ g3_bhh,
  const float* __restrict__ bn_gamma, const float* __restrict__ bn_beta,
  const float* __restrict__ bn_mean,  const float* __restrict__ bn_var,
  const float* __restrict__ fc_w, const float* __restrict__ fc_b,
  const float* __restrict__ reg_w, const float* __restrict__ reg_b,
  float* __restrict__ out)
{
  const int tid = threadIdx.x;
  const int bid = blockIdx.x;

  __shared__ __align__(16) float sx[H];
  __shared__ __align__(16) float sh[H];
  __shared__ float spre[2*H];
  __shared__ float sxn[H];
  __shared__ float shn[H];

  if (bid < NLAYERS) {
    // ---------------- g3 layer block: layer l ----------------
    const int l = bid;
    const float4* wih_row = (const float4*)(g3_wih + ((size_t)l*G3 + tid)*H);
    const float4* whh_row = (const float4*)(g3_whh + ((size_t)l*G3 + tid)*H);
    float4 whhr[40];
    float bihj = 0.f, bhhj = 0.f;
    if (tid < G3){
#pragma unroll
      for (int q = 0; q < 40; q++) whhr[q] = whh_row[q];
      bihj = g3_bih[l*G3 + tid];
      bhhj = g3_bhh[l*G3 + tid];
    }
    if (tid < H) sh[tid] = 0.f;

    // prefetch W_ih into L1/L2 ahead of the wavefront
    float pf = 0.f;
    if (tid < G3){
#pragma unroll
      for (int q = 0; q < 40; q++) pf += wih_row[q].x;
    }
    if (pf == 1.0e30f) spre[0] = pf;   // never true; defeats DCE
    __syncthreads();

    float hsum = 0.f;
    float* seq_in  = g_seq + (size_t)l * NCH * H;
    float* seq_out = g_seq + (size_t)(l+1) * NCH * H;

    for (int t = 0; t < NCH; t++){
      // recurrent dot first (off critical path: hides under the LLC
      // propagation window of the incoming chunk)
      float ahv = 0.f;
      if (tid < G3) ahv = bhhj + dot160(whhr, sh);
      if (tid < H) sx[tid] = poll_val(&seq_in[t*H + tid]);   // poll IS the load
      __syncthreads();
      if (tid < G3){
        float ax = bihj + dot160(wih_row, sx);
        if (tid < 2*H) spre[tid] = ax + ahv;
        else { sxn[tid - 2*H] = ax; shn[tid - 2*H] = ahv; }
      }
      __syncthreads();
      if (tid < H){
        float r = sigm(spre[tid]);
        float z = sigm(spre[H + tid]);
        float n = tanhf(sxn[tid] + r * shn[tid]);
        float h = (1.f - z) * n + z * sh[tid];
        sh[tid] = h;
        hsum += h;
        stf(&seq_out[t*H + tid], h);     // publish: no flag, no drain needed
      }
      __syncthreads();                   // sh stable before next ahv
    }

    if (l == NLAYERS - 1){
      // epilogue: x_cat_l (in-register), poll x_l, BN+ReLU, heads
      if (tid < H){
        float xc  = fmaxf(hsum * (1.0f / NCH), 0.f);
        float xl  = poll_val(&g_xlb[tid]);
        float xnew = xl * xc;
        float xbn  = (xnew - bn_mean[tid]) * rsqrtf(bn_var[tid] + 1e-5f)
                     * bn_gamma[tid] + bn_beta[tid];
        sx[tid] = fmaxf(xbn, 0.f);       // xr
      }
      __syncthreads();
      if (tid < NCLS + CC){
        const float* wrow; float acc;
        if (tid < NCLS){ wrow = fc_w + (size_t)tid * H; acc = fc_b[tid]; }
        else           { wrow = reg_w + (size_t)(tid - NCLS) * H; acc = reg_b[tid - NCLS]; }
#pragma unroll
        for (int q = 0; q < 40; q++){
          float4 wv = *(const float4*)(wrow + 4*q);
          float4 xv = *(const float4*)(sx + 4*q);
          acc = fmaf(wv.x, xv.x, acc);
          acc = fmaf(wv.y, xv.y, acc);
          acc = fmaf(wv.z, xv.z, acc);
          acc = fmaf(wv.w, xv.w, acc);
        }
        out[tid] = acc;                  // f32 output
      }
    }
  } else if (bid < NLAYERS + NCH) {
    // ---------------- branch GRU block b ----------------
    const int b = bid - NLAYERS;
    const float4* whh_row = (const float4*)(b_whh + ((size_t)b*G3 + tid)*H);
    float4 whhr[40];
    float wij = 0.f, bihj = 0.f, bhhj = 0.f;
    if (tid < G3){
#pragma unroll
      for (int q = 0; q < 40; q++) whhr[q] = whh_row[q];
      wij  = b_wih[b*G3 + tid];
      bihj = b_bih[b*G3 + tid];
      bhhj = b_bhh[b*G3 + tid];
    }
    if (tid < H) sh[tid] = 0.f;
    __syncthreads();
    for (int t = 0; t < TCH; t++){
      float xv = x[b*TCH + t];
      if (tid < G3){
        float ax = fmaf(xv, wij, bihj);
        float ah = bhhj + dot160(whhr, sh);
        if (tid < 2*H) spre[tid] = ax + ah;
        else { sxn[tid - 2*H] = ax; shn[tid - 2*H] = ah; }
      }
      __syncthreads();
      if (tid < H){
        float r = sigm(spre[tid]);
        float z = sigm(spre[H + tid]);
        float n = tanhf(sxn[tid] + r * shn[tid]);
        float h = (1.f - z) * n + z * sh[tid];
        sh[tid] = h;
        if (t == TCH - 1) stf(&g_seq[(size_t)b*H + tid], h);   // level 0, chunk b
      }
      __syncthreads();
    }
  } else {
    // ---------------- full-x GRU (200 steps) ----------------
    const float4* whh_row = (const float4*)(g_whh + (size_t)tid * H);
    float4 whhr[40];
    float wij = 0.f, bihj = 0.f, bhhj = 0.f;
    if (tid < G3){
#pragma unroll
      for (int q = 0; q < 40; q++) whhr[q] = whh_row[q];
      wij  = g_wih[tid];
      bihj = g_bih[tid];
      bhhj = g_bhh[tid];
    }
    if (tid < H) sh[tid] = 0.f;
    __syncthreads();
    float hsum = 0.f;
    for (int t = 0; t < CC; t++){
      float xv = x[t];
      if (tid < G3){
        float ax = fmaf(xv, wij, bihj);
        float ah = bhhj + dot160(whhr, sh);
        if (tid < 2*H) spre[tid] = ax + ah;
        else { sxn[tid - 2*H] = ax; shn[tid - 2*H] = ah; }
      }
      __syncthreads();
      if (tid < H){
        float r = sigm(spre[tid]);
        float z = sigm(spre[H + tid]);
        float n = tanhf(sxn[tid] + r * shn[tid]);
        float h = (1.f - z) * n + z * sh[tid];
        sh[tid] = h;
        hsum += h;
      }
      __syncthreads();
    }
    if (tid < H) stf(&g_xlb[tid], hsum * (1.0f / CC));   // publish x_l
  }
}

extern "C" void kernel_launch(void* const* d_in, const int* in_sizes, int n_in,
                              void* d_out, int out_size, void* d_ws, size_t ws_size,
                              hipStream_t stream) {
  (void)in_sizes; (void)n_in; (void)out_size; (void)d_ws; (void)ws_size;

  // re-poison the handoff buffers (stream-ordered before the wave kernel)
  hipLaunchKernelGGL(poison_kernel, dim3((NSEQ + 255)/256), dim3(256), 0, stream);

  dim3 grid(NLAYERS + NCH + 1);
  dim3 block(512);
  hipLaunchKernelGGL(spectral_wave, grid, block, 0, stream,
    (const float*)d_in[0],
    (const float*)d_in[1],  (const float*)d_in[2],
    (const float*)d_in[3],  (const float*)d_in[4],
    (const float*)d_in[5],  (const float*)d_in[6],
    (const float*)d_in[7],  (const float*)d_in[8],
    (const float*)d_in[9],  (const float*)d_in[10],
    (const float*)d_in[11], (const float*)d_in[12],
    (const float*)d_in[13], (const float*)d_in[14],
    (const float*)d_in[15], (const float*)d_in[16],
    (const float*)d_in[17], (const float*)d_in[18],
    (const float*)d_in[19], (const float*)d_in[20],
    (float*)d_out);
}

// Round 3
// 1453.072 us; speedup vs baseline: 2.7038x; 1.3150x over previous
//
#include <hip/hip_runtime.h>
#include <stdint.h>

#define H      160
#define G3     480
#define NCH    10
#define TCH    20
#define CC     200
#define NCLS   16
#define NLAYERS 160
#define NLEVELS 161
#define NSEQ   (NLEVELS * NCH * H)

// LDS-resident wih rows (f32). Pitch 164 floats (656 B, 16B-aligned):
// lane-to-lane bank stride = 164 mod 32 = 4, so a wave64 ds_read_b128 at
// row r, slot q hits banks {4r..4r+3} mod 32 — every 8 consecutive lanes
// cover all 32 banks exactly once = conflict-free-optimal for b128.
#define LROWS  240
#define LPITCH 164
#define LDS_WIH (LROWS * LPITCH)            // 39360 floats
#define LDS_TOT (LDS_WIH + H + H + 2*H + H + H)   // 40320 floats = 161280 B < 160 KiB

// Canary: quiet-NaN bit pattern. GRU hidden states are never NaN, so any
// legit value differs. Compare the BIT PATTERN (NaN float-compare is false).
#define CANARY 0x7fbadbadu

__device__ float g_seq[NSEQ];   // [161][10][160]
__device__ float g_xlb[H];

__device__ __forceinline__ float sigm(float x){ return 1.0f / (1.0f + expf(-x)); }

__device__ __forceinline__ void stf(float* p, float v){
  __hip_atomic_store(p, v, __ATOMIC_RELAXED, __HIP_MEMORY_SCOPE_AGENT);
}
__device__ __forceinline__ float ldf(float* p){
  return __hip_atomic_load(p, __ATOMIC_RELAXED, __HIP_MEMORY_SCOPE_AGENT);
}
// spin until *p != canary; the polled value IS the data (one one-way LLC
// propagation per handoff, zero fences, zero flags).
__device__ __forceinline__ float poll_val(float* p){
  float v;
  do { v = ldf(p); } while (__float_as_uint(v) == CANARY);
  return v;
}

__device__ __forceinline__ float dot160(const float4* __restrict__ w, const float* v){
  float a0 = 0.f, a1 = 0.f;
#pragma unroll
  for (int q = 0; q < 40; q += 2){
    float4 wa = w[q], wb = w[q+1];
    float4 va = *(const float4*)(v + 4*q);
    float4 vb = *(const float4*)(v + 4*q + 4);
    a0 = fmaf(wa.x, va.x, a0); a0 = fmaf(wa.y, va.y, a0);
    a0 = fmaf(wa.z, va.z, a0); a0 = fmaf(wa.w, va.w, a0);
    a1 = fmaf(wb.x, vb.x, a1); a1 = fmaf(wb.y, vb.y, a1);
    a1 = fmaf(wb.z, vb.z, a1); a1 = fmaf(wb.w, vb.w, a1);
  }
  return a0 + a1;
}

extern "C" __global__ void poison_kernel(){
  int i = threadIdx.x + blockIdx.x * blockDim.x;
  float c = __uint_as_float(CANARY);
  if (i < NSEQ) stf(&g_seq[i], c);
  if (i < H)    stf(&g_xlb[i], c);
}

// (512,1): 1 block/CU (also enforced by 161 KB LDS); whh row stays in the
// unified VGPR/AGPR file (no scratch). 171 blocks on 256 CUs: co-resident.
extern "C" __global__ __launch_bounds__(512, 1)
void spectral_wave(
  const float* __restrict__ x,
  const float* __restrict__ b_wih, const float* __restrict__ b_whh,
  const float* __restrict__ b_bih, const float* __restrict__ b_bhh,
  const float* __restrict__ g_wih, const float* __restrict__ g_whh,
  const float* __restrict__ g_bih, const float* __restrict__ g_bhh,
  const float* __restrict__ g3_wih, const float* __restrict__ g3_whh,
  const float* __restrict__ g3_bih, const float* __restrict__ g3_bhh,
  const float* __restrict__ bn_gamma, const float* __restrict__ bn_beta,
  const float* __restrict__ bn_mean,  const float* __restrict__ bn_var,
  const float* __restrict__ fc_w, const float* __restrict__ fc_b,
  const float* __restrict__ reg_w, const float* __restrict__ reg_b,
  float* __restrict__ out)
{
  const int tid = threadIdx.x;
  const int bid = blockIdx.x;

  __shared__ __align__(16) float s_all[LDS_TOT];
  float* s_wih = s_all;                 // [240][164]
  float* sx    = s_all + LDS_WIH;       // [160]
  float* sh    = sx + H;                // [160]
  float* spre  = sh + H;                // [320]
  float* sxn   = spre + 2*H;            // [160]
  float* shn   = sxn + H;               // [160]

  if (bid < NLAYERS) {
    // ---------------- g3 layer block: layer l ----------------
    const int l = bid;
    const float* wihL = g3_wih + (size_t)l * G3 * H;
    const float4* wih_row = (const float4*)(wihL + (size_t)tid * H);
    const float4* whh_row = (const float4*)(g3_whh + ((size_t)l*G3 + tid)*H);
    float4 whhr[40];
    float bihj = 0.f, bhhj = 0.f;
    if (tid < G3){
#pragma unroll
      for (int q = 0; q < 40; q++) whhr[q] = whh_row[q];
      bihj = g3_bih[l*G3 + tid];
      bhhj = g3_bhh[l*G3 + tid];
    }
    if (tid < H) sh[tid] = 0.f;

    // stage wih rows 0..239 into LDS (pitch 164), float4-coalesced:
    // 240*40 = 9600 float4s over 512 threads
    {
      const float4* src = (const float4*)wihL;
      float4* dst = (float4*)s_wih;        // pitch 41 float4
      for (int it = 0; it < 19; ++it){
        int i4 = it*512 + tid;
        if (i4 < LROWS*40){
          int r = i4 / 40, c = i4 - r*40;
          dst[r*41 + c] = src[i4];
        }
      }
    }
    // prefetch the STREAMED rows (240..479) into L1/L2 ahead of the wave
    float pf = 0.f;
    if (tid >= LROWS && tid < G3){
#pragma unroll
      for (int q = 0; q < 40; q++) pf += wih_row[q].x;
    }
    if (pf == 1.0e30f) spre[0] = pf;   // never true; defeats DCE
    __syncthreads();

    float hsum = 0.f;
    float* seq_in  = g_seq + (size_t)l * NCH * H;
    float* seq_out = g_seq + (size_t)(l+1) * NCH * H;

    for (int t = 0; t < NCH; t++){
      // recurrent dot first (off critical path: hides under the wait for
      // the incoming chunk)
      float ahv = 0.f;
      if (tid < G3) ahv = bhhj + dot160(whhr, sh);
      if (tid < H) sx[tid] = poll_val(&seq_in[t*H + tid]);   // poll IS the load
      __syncthreads();
      if (tid < G3){
        float ax;
        if (tid < LROWS) ax = bihj + dot160((const float4*)(s_wih + tid*LPITCH), sx);
        else             ax = bihj + dot160(wih_row, sx);
        if (tid < 2*H) spre[tid] = ax + ahv;
        else { sxn[tid - 2*H] = ax; shn[tid - 2*H] = ahv; }
      }
      __syncthreads();
      if (tid < H){
        float r = sigm(spre[tid]);
        float z = sigm(spre[H + tid]);
        float n = tanhf(sxn[tid] + r * shn[tid]);
        float h = (1.f - z) * n + z * sh[tid];
        sh[tid] = h;
        hsum += h;
        stf(&seq_out[t*H + tid], h);     // publish: no flag, no drain needed
      }
      __syncthreads();                   // sh stable before next ahv
    }

    if (l == NLAYERS - 1){
      // epilogue: x_cat_l (in-register), poll x_l, BN+ReLU, heads
      if (tid < H){
        float xc  = fmaxf(hsum * (1.0f / NCH), 0.f);
        float xl  = poll_val(&g_xlb[tid]);
        float xnew = xl * xc;
        float xbn  = (xnew - bn_mean[tid]) * rsqrtf(bn_var[tid] + 1e-5f)
                     * bn_gamma[tid] + bn_beta[tid];
        sx[tid] = fmaxf(xbn, 0.f);       // xr
      }
      __syncthreads();
      if (tid < NCLS + CC){
        const float* wrow; float acc;
        if (tid < NCLS){ wrow = fc_w + (size_t)tid * H; acc = fc_b[tid]; }
        else           { wrow = reg_w + (size_t)(tid - NCLS) * H; acc = reg_b[tid - NCLS]; }
#pragma unroll
        for (int q = 0; q < 40; q++){
          float4 wv = *(const float4*)(wrow + 4*q);
          float4 xv = *(const float4*)(sx + 4*q);
          acc = fmaf(wv.x, xv.x, acc);
          acc = fmaf(wv.y, xv.y, acc);
          acc = fmaf(wv.z, xv.z, acc);
          acc = fmaf(wv.w, xv.w, acc);
        }
        out[tid] = acc;                  // f32 output
      }
    }
  } else if (bid < NLAYERS + NCH) {
    // ---------------- branch GRU block b ----------------
    const int b = bid - NLAYERS;
    const float4* whh_row = (const float4*)(b_whh + ((size_t)b*G3 + tid)*H);
    float4 whhr[40];
    float wij = 0.f, bihj = 0.f, bhhj = 0.f;
    if (tid < G3){
#pragma unroll
      for (int q = 0; q < 40; q++) whhr[q] = whh_row[q];
      wij  = b_wih[b*G3 + tid];
      bihj = b_bih[b*G3 + tid];
      bhhj = b_bhh[b*G3 + tid];
    }
    if (tid < H) sh[tid] = 0.f;
    __syncthreads();
    for (int t = 0; t < TCH; t++){
      float xv = x[b*TCH + t];
      if (tid < G3){
        float ax = fmaf(xv, wij, bihj);
        float ah = bhhj + dot160(whhr, sh);
        if (tid < 2*H) spre[tid] = ax + ah;
        else { sxn[tid - 2*H] = ax; shn[tid - 2*H] = ah; }
      }
      __syncthreads();
      if (tid < H){
        float r = sigm(spre[tid]);
        float z = sigm(spre[H + tid]);
        float n = tanhf(sxn[tid] + r * shn[tid]);
        float h = (1.f - z) * n + z * sh[tid];
        sh[tid] = h;
        if (t == TCH - 1) stf(&g_seq[(size_t)b*H + tid], h);   // level 0, chunk b
      }
      __syncthreads();
    }
  } else {
    // ---------------- full-x GRU (200 steps) ----------------
    const float4* whh_row = (const float4*)(g_whh + (size_t)tid * H);
    float4 whhr[40];
    float wij = 0.f, bihj = 0.f, bhhj = 0.f;
    if (tid < G3){
#pragma unroll
      for (int q = 0; q < 40; q++) whhr[q] = whh_row[q];
      wij  = g_wih[tid];
      bihj = g_bih[tid];
      bhhj = g_bhh[tid];
    }
    if (tid < H) sh[tid] = 0.f;
    __syncthreads();
    float hsum = 0.f;
    for (int t = 0; t < CC; t++){
      float xv = x[t];
      if (tid < G3){
        float ax = fmaf(xv, wij, bihj);
        float ah = bhhj + dot160(whhr, sh);
        if (tid < 2*H) spre[tid] = ax + ah;
        else { sxn[tid - 2*H] = ax; shn[tid - 2*H] = ah; }
      }
      __syncthreads();
      if (tid < H){
        float r = sigm(spre[tid]);
        float z = sigm(spre[H + tid]);
        float n = tanhf(sxn[tid] + r * shn[tid]);
        float h = (1.f - z) * n + z * sh[tid];
        sh[tid] = h;
        hsum += h;
      }
      __syncthreads();
    }
    if (tid < H) stf(&g_xlb[tid], hsum * (1.0f / CC));   // publish x_l
  }
}

extern "C" void kernel_launch(void* const* d_in, const int* in_sizes, int n_in,
                              void* d_out, int out_size, void* d_ws, size_t ws_size,
                              hipStream_t stream) {
  (void)in_sizes; (void)n_in; (void)out_size; (void)d_ws; (void)ws_size;

  // re-poison the handoff buffers (stream-ordered before the wave kernel)
  hipLaunchKernelGGL(poison_kernel, dim3((NSEQ + 255)/256), dim3(256), 0, stream);

  dim3 grid(NLAYERS + NCH + 1);
  dim3 block(512);
  hipLaunchKernelGGL(spectral_wave, grid, block, 0, stream,
    (const float*)d_in[0],
    (const float*)d_in[1],  (const float*)d_in[2],
    (const float*)d_in[3],  (const float*)d_in[4],
    (const float*)d_in[5],  (const float*)d_in[6],
    (const float*)d_in[7],  (const float*)d_in[8],
    (const float*)d_in[9],  (const float*)d_in[10],
    (const float*)d_in[11], (const float*)d_in[12],
    (const float*)d_in[13], (const float*)d_in[14],
    (const float*)d_in[15], (const float*)d_in[16],
    (const float*)d_in[17], (const float*)d_in[18],
    (const float*)d_in[19], (const float*)d_in[20],
    (float*)d_out);
}

// Round 4
// 1304.156 us; speedup vs baseline: 3.0125x; 1.1142x over previous
//
#include <hip/hip_runtime.h>
#include <stdint.h>

#define H      160
#define G3     480
#define NCH    10
#define TCH    20
#define CC     200
#define NCLS   16
#define NLAYERS 160
#define NLEVELS 161
#define NSEQ   (NLEVELS * NCH * H)
#define NT     1024

// LDS-resident wih rows. Pitch 164 floats (656 B): rows 16B-aligned (both
// halves: 656r and 656r+320 are 16B multiples). Lane-to-lane bank stride
// 4 -> each 8 lanes cover all 32 banks; 16-lane phase = 2-way = free (m136).
#define LROWS  236
#define LP4    41
#define LPITCH (LP4*4)                 // 164 floats
#define LDS_WIH (LROWS * LPITCH)       // 38704 floats
// + sx(160) + sh(160) + spreH(2*320) + sxnH(2*160) + shnH(2*160)
#define LDS_TOT (LDS_WIH + 160 + 160 + 640 + 320 + 320)   // 40304 f = 161216 B

// Canary: quiet-NaN bit pattern. GRU hidden states are never NaN, so any
// legit value differs. Compare the BIT PATTERN (NaN float-compare is false).
#define CANARY 0x7fbadbadu

__device__ float g_seq[NSEQ];   // [161][10][160]
__device__ float g_xlb[H];

__device__ __forceinline__ float sigm(float x){ return 1.0f / (1.0f + expf(-x)); }

__device__ __forceinline__ void stf(float* p, float v){
  __hip_atomic_store(p, v, __ATOMIC_RELAXED, __HIP_MEMORY_SCOPE_AGENT);
}
__device__ __forceinline__ float ldf(float* p){
  return __hip_atomic_load(p, __ATOMIC_RELAXED, __HIP_MEMORY_SCOPE_AGENT);
}
// spin until *p != canary; the polled value IS the data (one one-way LLC
// propagation per handoff, zero fences, zero flags).
__device__ __forceinline__ float poll_val(float* p){
  float v;
  do { v = ldf(p); } while (__float_as_uint(v) == CANARY);
  return v;
}

// 80-MAC half-dot: w = 20 contiguous float4 (regs after SROA, LDS, or global),
// v = 80 contiguous floats (LDS).
__device__ __forceinline__ float dot80(const float4* __restrict__ w,
                                       const float* __restrict__ v){
  float a0 = 0.f, a1 = 0.f;
#pragma unroll
  for (int q = 0; q < 20; q += 2){
    float4 wa = w[q], wb = w[q+1];
    float4 va = *(const float4*)(v + 4*q);
    float4 vb = *(const float4*)(v + 4*q + 4);
    a0 = fmaf(wa.x, va.x, a0); a0 = fmaf(wa.y, va.y, a0);
    a0 = fmaf(wa.z, va.z, a0); a0 = fmaf(wa.w, va.w, a0);
    a1 = fmaf(wb.x, vb.x, a1); a1 = fmaf(wb.y, vb.y, a1);
    a1 = fmaf(wb.z, vb.z, a1); a1 = fmaf(wb.w, vb.w, a1);
  }
  return a0 + a1;
}

extern "C" __global__ void poison_kernel(){
  int i = threadIdx.x + blockIdx.x * blockDim.x;
  float c = __uint_as_float(CANARY);
  if (i < NSEQ) stf(&g_seq[i], c);
  if (i < H)    stf(&g_xlb[i], c);
}

// NT=1024: 16 waves -> 4 waves/SIMD -> 128-VGPR cap. whh HALF-row = 20
// float4 = 80 VGPRs: genuinely register-resident (no spill, no L2 stream).
// LDS 161 KB -> 1 block/CU; 171 blocks co-resident on 256 CUs.
extern "C" __global__ __launch_bounds__(NT, 1)
void spectral_wave(
  const float* __restrict__ x,
  const float* __restrict__ b_wih, const float* __restrict__ b_whh,
  const float* __restrict__ b_bih, const float* __restrict__ b_bhh,
  const float* __restrict__ g_wih, const float* __restrict__ g_whh,
  const float* __restrict__ g_bih, const float* __restrict__ g_bhh,
  const float* __restrict__ g3_wih, const float* __restrict__ g3_whh,
  const float* __restrict__ g3_bih, const float* __restrict__ g3_bhh,
  const float* __restrict__ bn_gamma, const float* __restrict__ bn_beta,
  const float* __restrict__ bn_mean,  const float* __restrict__ bn_var,
  const float* __restrict__ fc_w, const float* __restrict__ fc_b,
  const float* __restrict__ reg_w, const float* __restrict__ reg_b,
  float* __restrict__ out)
{
  const int tid = threadIdx.x;
  const int bid = blockIdx.x;
  const bool act = tid < 960;            // waves 0..14 active in dots
  const int r  = act ? (tid % 480) : 0;  // output row
  const int hf = act ? (tid / 480) : 0;  // K-half: 0 -> cols 0..79, 1 -> 80..159
  const int c0 = 80 * hf;

  __shared__ __align__(16) float s_all[LDS_TOT];
  float* s_wih = s_all;                  // [236][164]
  float* sx    = s_all + LDS_WIH;        // [160]
  float* sh    = sx + H;                 // [160]
  float* spreH = sh + H;                 // [2][320]  combined (ax+ah) rows 0..319
  float* sxnH  = spreH + 640;            // [2][160]  ax rows 320..479
  float* shnH  = sxnH + 320;             // [2][160]  ah rows 320..479

  if (bid < NLAYERS) {
    // ---------------- g3 layer block: layer l ----------------
    const int l = bid;
    const float* wihL = g3_wih + (size_t)l * G3 * H;

    // whh half-row -> registers (80 VGPRs). Bias carried by half A only.
    float4 whr[20];
    float bihj = 0.f, bhhj = 0.f;
    if (act){
      const float4* wsrc = (const float4*)(g3_whh + ((size_t)l*G3 + r)*H + c0);
#pragma unroll
      for (int q = 0; q < 20; q++) whr[q] = wsrc[q];
      if (hf == 0){ bihj = g3_bih[l*G3 + r]; bhhj = g3_bhh[l*G3 + r]; }
    }
    if (tid < H) sh[tid] = 0.f;

    // stage wih rows 0..235 into LDS (full rows), float4-coalesced
    {
      const float4* src = (const float4*)wihL;
      float4* dst = (float4*)s_wih;      // pitch LP4=41 float4
      for (int it = 0; it < 10; ++it){
        int i4 = it*NT + tid;
        if (i4 < LROWS*40){
          int rr = i4 / 40, cc = i4 - rr*40;
          dst[rr*LP4 + cc] = src[rr*40 + cc];
        }
      }
    }
    // prefetch streamed rows (236..479) into L2 ahead of the wave
    float pf = 0.f;
    if (act && r >= LROWS){
      const float4* g = (const float4*)(wihL + (size_t)r*H + c0);
#pragma unroll
      for (int q = 0; q < 20; q++) pf += g[q].x;
    }
    if (pf == 1.0e30f) spreH[0] = pf;    // never true; defeats DCE
    __syncthreads();

    // wih half source: LDS for rows < LROWS, global (L2-resident) otherwise
    const float4* wxp = (r < LROWS)
        ? (const float4*)(s_wih + r*LPITCH + c0)
        : (const float4*)(wihL + (size_t)r*H + c0);

    float hsum = 0.f;
    float* seq_in  = g_seq + (size_t)l * NCH * H;
    float* seq_out = g_seq + (size_t)(l+1) * NCH * H;

    for (int t = 0; t < NCH; t++){
      // recurrent half-dot from REGISTERS (cheap, pre-poll)
      float s_h = 0.f;
      if (act) s_h = bhhj + dot80(whr, sh + c0);
      if (tid < H) sx[tid] = poll_val(&seq_in[t*H + tid]);   // poll IS the load
      __syncthreads();
      if (act){
        float s_w = bihj + dot80(wxp, sx + c0);
        if (r < 2*H) spreH[hf*320 + r] = s_w + s_h;
        else { sxnH[hf*160 + (r-320)] = s_w; shnH[hf*160 + (r-320)] = s_h; }
      }
      __syncthreads();
      if (tid < H){
        float pr = spreH[tid]     + spreH[320 + tid];
        float pz = spreH[H + tid] + spreH[320 + H + tid];
        float xn = sxnH[tid]      + sxnH[160 + tid];
        float hn = shnH[tid]      + shnH[160 + tid];
        float rg = sigm(pr);
        float z  = sigm(pz);
        float n  = tanhf(xn + rg * hn);
        float h  = (1.f - z) * n + z * sh[tid];
        sh[tid] = h;
        hsum += h;
        stf(&seq_out[t*H + tid], h);     // publish: no flag, no drain needed
      }
      __syncthreads();                   // sh stable before next s_h
    }

    if (l == NLAYERS - 1){
      // epilogue: x_cat_l (in-register), poll x_l, BN+ReLU, heads
      if (tid < H){
        float xc   = fmaxf(hsum * (1.0f / NCH), 0.f);
        float xl   = poll_val(&g_xlb[tid]);
        float xnew = xl * xc;
        float xbn  = (xnew - bn_mean[tid]) * rsqrtf(bn_var[tid] + 1e-5f)
                     * bn_gamma[tid] + bn_beta[tid];
        sx[tid] = fmaxf(xbn, 0.f);       // xr
      }
      __syncthreads();
      if (tid < NCLS + CC){
        const float* wrow; float acc;
        if (tid < NCLS){ wrow = fc_w + (size_t)tid * H; acc = fc_b[tid]; }
        else           { wrow = reg_w + (size_t)(tid - NCLS) * H; acc = reg_b[tid - NCLS]; }
#pragma unroll
        for (int q = 0; q < 40; q++){
          float4 wv = *(const float4*)(wrow + 4*q);
          float4 xv = *(const float4*)(sx + 4*q);
          acc = fmaf(wv.x, xv.x, acc);
          acc = fmaf(wv.y, xv.y, acc);
          acc = fmaf(wv.z, xv.z, acc);
          acc = fmaf(wv.w, xv.w, acc);
        }
        out[tid] = acc;                  // f32 output
      }
    }
  } else if (bid < NLAYERS + NCH) {
    // ---------------- branch GRU block b ----------------
    const int b = bid - NLAYERS;
    float4 whr[20];
    float wij = 0.f, bihj = 0.f, bhhj = 0.f;
    if (act){
      const float4* wsrc = (const float4*)(b_whh + ((size_t)b*G3 + r)*H + c0);
#pragma unroll
      for (int q = 0; q < 20; q++) whr[q] = wsrc[q];
      if (hf == 0){
        wij  = b_wih[b*G3 + r];
        bihj = b_bih[b*G3 + r];
        bhhj = b_bhh[b*G3 + r];
      }
    }
    if (tid < H) sh[tid] = 0.f;
    __syncthreads();
    for (int t = 0; t < TCH; t++){
      float xv = x[b*TCH + t];
      if (act){
        float s_h = bhhj + dot80(whr, sh + c0);
        float s_w = (hf == 0) ? fmaf(xv, wij, bihj) : 0.f;
        if (r < 2*H) spreH[hf*320 + r] = s_w + s_h;
        else { sxnH[hf*160 + (r-320)] = s_w; shnH[hf*160 + (r-320)] = s_h; }
      }
      __syncthreads();
      if (tid < H){
        float pr = spreH[tid]     + spreH[320 + tid];
        float pz = spreH[H + tid] + spreH[320 + H + tid];
        float xn = sxnH[tid]      + sxnH[160 + tid];
        float hn = shnH[tid]      + shnH[160 + tid];
        float rg = sigm(pr);
        float z  = sigm(pz);
        float n  = tanhf(xn + rg * hn);
        float h  = (1.f - z) * n + z * sh[tid];
        sh[tid] = h;
        if (t == TCH - 1) stf(&g_seq[(size_t)b*H + tid], h);   // level 0, chunk b
      }
      __syncthreads();
    }
  } else {
    // ---------------- full-x GRU (200 steps) ----------------
    float4 whr[20];
    float wij = 0.f, bihj = 0.f, bhhj = 0.f;
    if (act){
      const float4* wsrc = (const float4*)(g_whh + (size_t)r*H + c0);
#pragma unroll
      for (int q = 0; q < 20; q++) whr[q] = wsrc[q];
      if (hf == 0){
        wij  = g_wih[r];
        bihj = g_bih[r];
        bhhj = g_bhh[r];
      }
    }
    if (tid < H) sh[tid] = 0.f;
    __syncthreads();
    float hsum = 0.f;
    for (int t = 0; t < CC; t++){
      float xv = x[t];
      if (act){
        float s_h = bhhj + dot80(whr, sh + c0);
        float s_w = (hf == 0) ? fmaf(xv, wij, bihj) : 0.f;
        if (r < 2*H) spreH[hf*320 + r] = s_w + s_h;
        else { sxnH[hf*160 + (r-320)] = s_w; shnH[hf*160 + (r-320)] = s_h; }
      }
      __syncthreads();
      if (tid < H){
        float pr = spreH[tid]     + spreH[320 + tid];
        float pz = spreH[H + tid] + spreH[320 + H + tid];
        float xn = sxnH[tid]      + sxnH[160 + tid];
        float hn = shnH[tid]      + shnH[160 + tid];
        float rg = sigm(pr);
        float z  = sigm(pz);
        float n  = tanhf(xn + rg * hn);
        float h  = (1.f - z) * n + z * sh[tid];
        sh[tid] = h;
        hsum += h;
      }
      __syncthreads();
    }
    if (tid < H) stf(&g_xlb[tid], hsum * (1.0f / CC));   // publish x_l
  }
}

extern "C" void kernel_launch(void* const* d_in, const int* in_sizes, int n_in,
                              void* d_out, int out_size, void* d_ws, size_t ws_size,
                              hipStream_t stream) {
  (void)in_sizes; (void)n_in; (void)out_size; (void)d_ws; (void)ws_size;

  // re-poison the handoff buffers (stream-ordered before the wave kernel)
  hipLaunchKernelGGL(poison_kernel, dim3((NSEQ + 255)/256), dim3(256), 0, stream);

  dim3 grid(NLAYERS + NCH + 1);
  dim3 block(NT);
  hipLaunchKernelGGL(spectral_wave, grid, block, 0, stream,
    (const float*)d_in[0],
    (const float*)d_in[1],  (const float*)d_in[2],
    (const float*)d_in[3],  (const float*)d_in[4],
    (const float*)d_in[5],  (const float*)d_in[6],
    (const float*)d_in[7],  (const float*)d_in[8],
    (const float*)d_in[9],  (const float*)d_in[10],
    (const float*)d_in[11], (const float*)d_in[12],
    (const float*)d_in[13], (const float*)d_in[14],
    (const float*)d_in[15], (const float*)d_in[16],
    (const float*)d_in[17], (const float*)d_in[18],
    (const float*)d_in[19], (const float*)d_in[20],
    (float*)d_out);
}